// Round 12
// baseline (345.100 us; speedup 1.0000x reference)
//
#include <hip/hip_runtime.h>
#include <hip/hip_bf16.h>
#include <stdint.h>

// Problem constants
constexpr int IN_F  = 4096;
constexpr int OUT_F = 4096;
constexpr int M_ROWS = 4 * 2048;   // 8192
constexpr int RANK = 16;

typedef short short8 __attribute__((ext_vector_type(8)));
typedef float f32x16 __attribute__((ext_vector_type(16)));

__device__ __forceinline__ short f2bf(float f) {
  return __builtin_bit_cast(short, __float2bfloat16(f));
}

__device__ __forceinline__ void gload16(const void* g, void* l) {
  __builtin_amdgcn_global_load_lds(
      (const __attribute__((address_space(1))) void*)g,
      (__attribute__((address_space(3))) void*)l, 16, 0, 0);
}

// ---------------------------------------------------------------------------
// Kernel 1 (fused): blocks 0..511 dequantize+LoRA-fold W_eff; blocks 512..2559
// convert x fp32->bf16.
// ---------------------------------------------------------------------------
__global__ __launch_bounds__(256) void prep_kernel(
    const int* __restrict__ q,        // packed bytes, one byte per int32
    const float* __restrict__ wmax,
    const float* __restrict__ lut,
    const float* __restrict__ lA,     // [RANK][IN_F]
    const float* __restrict__ lB,     // [OUT_F][RANK]
    const float* __restrict__ x,
    __hip_bfloat16* __restrict__ W,   // [OUT_F][IN_F]
    __hip_bfloat16* __restrict__ xb) {
  if (blockIdx.x < 512) {
    __shared__ float slut[16];
    if (threadIdx.x < 16) slut[threadIdx.x] = lut[threadIdx.x];
    __syncthreads();

    const int bx = blockIdx.x & 7, by = blockIdx.x >> 3;
    const int o0  = by * 64 + (threadIdx.x >> 5) * 8;
    const int ib0 = bx * 512 + (threadIdx.x & 31) * 16;

    #pragma unroll
    for (int h = 0; h < 2; ++h) {
      const int ib = ib0 + h * 8;
      float w[8][8];
      #pragma unroll
      for (int p = 0; p < 8; ++p) {
        const size_t l = (size_t)(o0 + p) * IN_F + ib;
        const int4 u = *(const int4*)(q + (l >> 1));
        const float sc = wmax[l >> 6];
        w[p][0] = slut[u.x & 15] * sc;
        w[p][1] = slut[(u.x >> 4) & 15] * sc;
        w[p][2] = slut[u.y & 15] * sc;
        w[p][3] = slut[(u.y >> 4) & 15] * sc;
        w[p][4] = slut[u.z & 15] * sc;
        w[p][5] = slut[(u.z >> 4) & 15] * sc;
        w[p][6] = slut[u.w & 15] * sc;
        w[p][7] = slut[(u.w >> 4) & 15] * sc;
      }
      #pragma unroll 2
      for (int r = 0; r < 16; ++r) {
        const float* ar = lA + (size_t)r * IN_F + ib;
        const float4 a0 = *(const float4*)(ar);
        const float4 a1 = *(const float4*)(ar + 4);
        float b[8];
        #pragma unroll
        for (int p = 0; p < 8; ++p) b[p] = lB[(size_t)(o0 + p) * RANK + r];
        #pragma unroll
        for (int p = 0; p < 8; ++p) {
          w[p][0] += b[p] * a0.x; w[p][1] += b[p] * a0.y;
          w[p][2] += b[p] * a0.z; w[p][3] += b[p] * a0.w;
          w[p][4] += b[p] * a1.x; w[p][5] += b[p] * a1.y;
          w[p][6] += b[p] * a1.z; w[p][7] += b[p] * a1.w;
        }
      }
      #pragma unroll
      for (int p = 0; p < 8; ++p) {
        short8 s;
        #pragma unroll
        for (int qq = 0; qq < 8; ++qq) s[qq] = f2bf(w[p][qq]);
        *(short8*)&W[(size_t)(o0 + p) * IN_F + ib] = s;
      }
    }
  } else {
    constexpr int NG = (M_ROWS * IN_F) / 8;
    const int stride = 2048 * 256;
    for (int i = (blockIdx.x - 512) * 256 + threadIdx.x; i < NG; i += stride) {
      const float4 a = ((const float4*)x)[2 * i];
      const float4 b = ((const float4*)x)[2 * i + 1];
      short8 s;
      s[0] = f2bf(a.x); s[1] = f2bf(a.y); s[2] = f2bf(a.z); s[3] = f2bf(a.w);
      s[4] = f2bf(b.x); s[5] = f2bf(b.y); s[6] = f2bf(b.z); s[7] = f2bf(b.w);
      ((short8*)xb)[i] = s;
    }
  }
}

// ---------------------------------------------------------------------------
// Kernel 2: 256x256-tile 8-phase GEMM, 32x32x16 MFMA — R12 stream-order fix:
// (1) ds_read issue order ks-OUTER so consecutive reads hit rows 32 apart
//     (R5's conflict-free stream adjacency), not the same rows (R11);
// (2) MFMA issue order ks-OUTER so same-acc-cell MFMAs are 4 apart (R11 had
//     back-to-back dependent MFMAs, dep distance 1).
// Layout/swizzle/phases/vmcnt identical to R11 (absmax-verified).
// ---------------------------------------------------------------------------
constexpr int BM = 256, BN = 256, BK = 64;
constexpr int GM = M_ROWS, GN = OUT_F, GK = IN_F;
constexpr int NKT = GK / BK;  // 64

#define LOAD_B32(BUF, KH)                                                 \
  _Pragma("unroll")                                                       \
  for (int ks_ = 0; ks_ < 2; ++ks_)                                       \
    _Pragma("unroll")                                                     \
    for (int nt_ = 0; nt_ < 2; ++nt_)                                     \
      bf[nt_][ks_] = *(const short8*)&sB[BUF][KH][wn * 64 + nt_ * 32 + l31][(((ks_ * 2 + lhi) ^ swz) * 8)];

#define LOAD_A32(BUF, KH, MH)                                             \
  _Pragma("unroll")                                                       \
  for (int ks_ = 0; ks_ < 2; ++ks_)                                       \
    _Pragma("unroll")                                                     \
    for (int mt_ = 0; mt_ < 2; ++mt_)                                     \
      af[mt_][ks_] = *(const short8*)&sA[BUF][KH][wm * 128 + (MH) * 64 + mt_ * 32 + l31][(((ks_ * 2 + lhi) ^ swz) * 8)];

#define MFMA_Q32(MH)                                                      \
  __builtin_amdgcn_s_setprio(1);                                          \
  _Pragma("unroll")                                                       \
  for (int ks_ = 0; ks_ < 2; ++ks_)                                       \
    _Pragma("unroll")                                                     \
    for (int mt_ = 0; mt_ < 2; ++mt_)                                     \
      _Pragma("unroll")                                                   \
      for (int nt_ = 0; nt_ < 2; ++nt_)                                   \
        acc[(MH) * 2 + mt_][nt_] = __builtin_amdgcn_mfma_f32_32x32x16_bf16( \
            af[mt_][ks_], bf[nt_][ks_], acc[(MH) * 2 + mt_][nt_], 0, 0, 0); \
  __builtin_amdgcn_s_setprio(0);

#define PHASE(BUF, KH, MH, DOB, GB, LB, VM)                               \
  do {                                                                    \
    if (DOB) { LOAD_B32(BUF, KH) }                                        \
    LOAD_A32(BUF, KH, MH)                                                 \
    stage(GB, LB);                                                        \
    if (VM) asm volatile("s_waitcnt vmcnt(6)" ::: "memory");              \
    __builtin_amdgcn_s_barrier();                                         \
    MFMA_Q32(MH)                                                          \
    __builtin_amdgcn_sched_barrier(0);                                    \
    __builtin_amdgcn_s_barrier();                                         \
  } while (0)

__global__ __launch_bounds__(512, 2) void gemm_bt_32r(
    const __hip_bfloat16* __restrict__ A,  // [M][K] bf16
    const __hip_bfloat16* __restrict__ B,  // [N][K] bf16
    const float* __restrict__ bias,        // [N]
    float* __restrict__ C) {               // [M][N] fp32
  __shared__ __hip_bfloat16 sA[2][2][256][32];  // 64 KiB
  __shared__ __hip_bfloat16 sB[2][2][256][32];  // 64 KiB

  const int tid  = threadIdx.x;
  const int lane = tid & 63;
  const int wave = tid >> 6;
  const int l31 = lane & 31;
  const int lhi = lane >> 5;
  const int wm = wave >> 2;   // 0..1
  const int wn = wave & 3;    // 0..3
  // fragment rows differ from l31 by multiples of 32 -> per-lane constant
  const int swz = (l31 >> 1) & 3;

  // T1: XCD-aware swizzle (nwg=512, %8==0 -> bijective)
  const int bid = blockIdx.x;
  const int cpx = gridDim.x >> 3;
  const int wg  = (bid & 7) * cpx + (bid >> 3);
  const int nbn = GN / BN;    // 16
  const int m0 = (wg / nbn) * BM;
  const int n0 = (wg % nbn) * BN;

  const __hip_bfloat16* Abase = A + (size_t)m0 * GK;
  const __hip_bfloat16* Bbase = B + (size_t)n0 * GK;

  // stage one 256x32 K-half region (16 KiB): 1024 granules, 2 gload16/thread.
  // Physical granule (row=c>>2, sp=c&3) receives global slot sp ^ ((row>>1)&3).
  const int swst = (tid >> 3) & 3;
  auto stage = [&](const __hip_bfloat16* gb, __hip_bfloat16* lb) {
    #pragma unroll
    for (int j = 0; j < 2; ++j) {
      const int c = j * 512 + tid;
      const int row = c >> 2, slot = c & 3;
      const int sg = slot ^ swst;
      gload16(gb + (size_t)row * GK + sg * 8,
              (void*)((char*)lb + (j * 512 + wave * 64) * 16));
    }
  };

  f32x16 acc[4][2];
  #pragma unroll
  for (int m = 0; m < 4; ++m)
    #pragma unroll
    for (int n = 0; n < 2; ++n) acc[m][n] = (f32x16)0.0f;

  // Prologue: tile0 fully + tile1 {Bk0, Ak0, Bk1} = 14 VMEM instr;
  // vmcnt(6) -> stages 1-4 (sA00,sB00,sA01,sB01) complete.
  stage(Abase +  0, &sA[0][0][0][0]);
  stage(Bbase +  0, &sB[0][0][0][0]);
  stage(Abase + 32, &sA[0][1][0][0]);
  stage(Bbase + 32, &sB[0][1][0][0]);
  stage(Bbase + 64, &sB[1][0][0][0]);
  stage(Abase + 64, &sA[1][0][0][0]);
  stage(Bbase + 96, &sB[1][1][0][0]);
  asm volatile("s_waitcnt vmcnt(6)" ::: "memory");
  __builtin_amdgcn_s_barrier();

  short8 af[2][2], bf[2][2];

  for (int t = 0; t < NKT; t += 2) {
    // clamp keeps vmcnt counting exact on the last iterations; clamped
    // stages land only in regions that are never read again.
    const int t2 = (t + 2 < NKT) ? t + 2 : NKT - 1;
    const int t3 = (t + 3 < NKT) ? t + 3 : NKT - 1;

    PHASE(0, 0, 0, true,  Abase + (size_t)(t + 1) * 64 + 32, &sA[1][1][0][0], false);
    PHASE(0, 0, 1, false, Bbase + (size_t)t2 * 64,           &sB[0][0][0][0], false);
    PHASE(0, 1, 0, true,  Abase + (size_t)t2 * 64,           &sA[0][0][0][0], false);
    PHASE(0, 1, 1, false, Bbase + (size_t)t2 * 64 + 32,      &sB[0][1][0][0], true);
    PHASE(1, 0, 0, true,  Abase + (size_t)t2 * 64 + 32,      &sA[0][1][0][0], false);
    PHASE(1, 0, 1, false, Bbase + (size_t)t3 * 64,           &sB[1][0][0][0], false);
    PHASE(1, 1, 0, true,  Abase + (size_t)t3 * 64,           &sA[1][0][0][0], false);
    PHASE(1, 1, 1, false, Bbase + (size_t)t3 * 64 + 32,      &sB[1][1][0][0], true);
  }

  // epilogue: C = acc + bias.  32x32 C/D: col=lane&31,
  // row = (reg&3) + 8*(reg>>2) + 4*(lane>>5).
  #pragma unroll
  for (int nt = 0; nt < 2; ++nt) {
    const int col = n0 + wn * 64 + nt * 32 + l31;
    const float bv = bias[col];
    #pragma unroll
    for (int amt = 0; amt < 4; ++amt) {
      const int rb = m0 + wm * 128 + amt * 32 + 4 * lhi;
      #pragma unroll
      for (int reg = 0; reg < 16; ++reg) {
        const int row = rb + (reg & 3) + 8 * (reg >> 2);
        C[(size_t)row * GN + col] = acc[amt][nt][reg] + bv;
      }
    }
  }
}

// ---------------------------------------------------------------------------
extern "C" void kernel_launch(void* const* d_in, const int* in_sizes, int n_in,
                              void* d_out, int out_size, void* d_ws, size_t ws_size,
                              hipStream_t stream) {
  const float* x    = (const float*)d_in[0];
  const int*   qw   = (const int*)d_in[1];
  const float* wmax = (const float*)d_in[2];
  const float* lut  = (const float*)d_in[3];
  const float* lA   = (const float*)d_in[4];
  const float* lB   = (const float*)d_in[5];
  const float* bias = (const float*)d_in[6];
  float* out = (float*)d_out;

  __hip_bfloat16* Weff = (__hip_bfloat16*)d_ws;                       // 33.5 MB
  __hip_bfloat16* xb   = (__hip_bfloat16*)((char*)d_ws + (size_t)OUT_F * IN_F * 2); // 67 MB

  prep_kernel<<<2560, 256, 0, stream>>>(qw, wmax, lut, lA, lB, x, Weff, xb);
  gemm_bt_32r<<<(GM / BM) * (GN / BN), 512, 0, stream>>>(xb, Weff, bias, out);
}

// Round 13
// 315.096 us; speedup vs baseline: 1.0952x; 1.0952x over previous
//
#include <hip/hip_runtime.h>
#include <hip/hip_bf16.h>
#include <stdint.h>

// Problem constants
constexpr int IN_F  = 4096;
constexpr int OUT_F = 4096;
constexpr int M_ROWS = 4 * 2048;   // 8192
constexpr int RANK = 16;

typedef short short8 __attribute__((ext_vector_type(8)));
typedef float f32x4 __attribute__((ext_vector_type(4)));

__device__ __forceinline__ short f2bf(float f) {
  return __builtin_bit_cast(short, __float2bfloat16(f));
}

__device__ __forceinline__ void gload16(const void* g, void* l) {
  __builtin_amdgcn_global_load_lds(
      (const __attribute__((address_space(1))) void*)g,
      (__attribute__((address_space(3))) void*)l, 16, 0, 0);
}

// ---------------------------------------------------------------------------
// Kernel 1 (fused): blocks 0..511 dequantize+LoRA-fold W_eff; blocks 512..2559
// convert x fp32->bf16.  Both HBM-bound; fused to share the BW window.
// ---------------------------------------------------------------------------
__global__ __launch_bounds__(256) void prep_kernel(
    const int* __restrict__ q,        // packed bytes, one byte per int32
    const float* __restrict__ wmax,
    const float* __restrict__ lut,
    const float* __restrict__ lA,     // [RANK][IN_F]
    const float* __restrict__ lB,     // [OUT_F][RANK]
    const float* __restrict__ x,
    __hip_bfloat16* __restrict__ W,   // [OUT_F][IN_F]
    __hip_bfloat16* __restrict__ xb) {
  if (blockIdx.x < 512) {
    __shared__ float slut[16];
    if (threadIdx.x < 16) slut[threadIdx.x] = lut[threadIdx.x];
    __syncthreads();

    const int bx = blockIdx.x & 7, by = blockIdx.x >> 3;
    const int o0  = by * 64 + (threadIdx.x >> 5) * 8;
    const int ib0 = bx * 512 + (threadIdx.x & 31) * 16;

    #pragma unroll
    for (int h = 0; h < 2; ++h) {
      const int ib = ib0 + h * 8;
      float w[8][8];
      #pragma unroll
      for (int p = 0; p < 8; ++p) {
        const size_t l = (size_t)(o0 + p) * IN_F + ib;
        const int4 u = *(const int4*)(q + (l >> 1));
        const float sc = wmax[l >> 6];
        w[p][0] = slut[u.x & 15] * sc;
        w[p][1] = slut[(u.x >> 4) & 15] * sc;
        w[p][2] = slut[u.y & 15] * sc;
        w[p][3] = slut[(u.y >> 4) & 15] * sc;
        w[p][4] = slut[u.z & 15] * sc;
        w[p][5] = slut[(u.z >> 4) & 15] * sc;
        w[p][6] = slut[u.w & 15] * sc;
        w[p][7] = slut[(u.w >> 4) & 15] * sc;
      }
      #pragma unroll 2
      for (int r = 0; r < 16; ++r) {
        const float* ar = lA + (size_t)r * IN_F + ib;
        const float4 a0 = *(const float4*)(ar);
        const float4 a1 = *(const float4*)(ar + 4);
        float b[8];
        #pragma unroll
        for (int p = 0; p < 8; ++p) b[p] = lB[(size_t)(o0 + p) * RANK + r];
        #pragma unroll
        for (int p = 0; p < 8; ++p) {
          w[p][0] += b[p] * a0.x; w[p][1] += b[p] * a0.y;
          w[p][2] += b[p] * a0.z; w[p][3] += b[p] * a0.w;
          w[p][4] += b[p] * a1.x; w[p][5] += b[p] * a1.y;
          w[p][6] += b[p] * a1.z; w[p][7] += b[p] * a1.w;
        }
      }
      #pragma unroll
      for (int p = 0; p < 8; ++p) {
        short8 s;
        #pragma unroll
        for (int qq = 0; qq < 8; ++qq) s[qq] = f2bf(w[p][qq]);
        *(short8*)&W[(size_t)(o0 + p) * IN_F + ib] = s;
      }
    }
  } else {
    constexpr int NG = (M_ROWS * IN_F) / 8;
    const int stride = 2048 * 256;
    for (int i = (blockIdx.x - 512) * 256 + threadIdx.x; i < NG; i += stride) {
      const float4 a = ((const float4*)x)[2 * i];
      const float4 b = ((const float4*)x)[2 * i + 1];
      short8 s;
      s[0] = f2bf(a.x); s[1] = f2bf(a.y); s[2] = f2bf(a.z); s[3] = f2bf(a.w);
      s[4] = f2bf(b.x); s[5] = f2bf(b.y); s[6] = f2bf(b.z); s[7] = f2bf(b.w);
      ((short8*)xb)[i] = s;
    }
  }
}

// ---------------------------------------------------------------------------
// Kernel 2: 256x256-tile 8-phase bf16 MFMA GEMM — exact R5 structure (best
// and tightest of 10 measured variants: 282.0-283.6us, MfmaUtil 43.5,
// 0 bank conflicts), plus nontemporal C stores (C stream no longer evicts
// A/B panels from L2/L3 -> lower HBM refetch).
// 512 thr = 8 waves (2Mx4N), per-wave 128x64 out, BK=64 (2 k-halves).
// LDS [256][32] K-half regions, slot-XOR swizzle (row,sp)->(row,sp^((row>>1)&3)):
// linear gload_lds dest + pre-swizzled global source + same XOR on ds_read.
// vmcnt(6) at phases 4/8 only (3 half-tiles in flight, never drained to 0).
// ---------------------------------------------------------------------------
constexpr int BM = 256, BN = 256, BK = 64;
constexpr int GM = M_ROWS, GN = OUT_F, GK = IN_F;
constexpr int NKT = GK / BK;  // 64

#define LOAD_B(BUF, KH)                                                   \
  _Pragma("unroll")                                                       \
  for (int n_ = 0; n_ < 4; ++n_)                                          \
    bf[n_] = *(const short8*)&sB[BUF][KH][wn * 64 + n_ * 16 + lr][swr * 8];

#define LOAD_A(BUF, KH, MH)                                               \
  _Pragma("unroll")                                                       \
  for (int i_ = 0; i_ < 4; ++i_)                                          \
    af[i_] = *(const short8*)&sA[BUF][KH][wm * 128 + (MH) * 64 + i_ * 16 + lr][swr * 8];

#define MFMA_Q(MH)                                                        \
  __builtin_amdgcn_s_setprio(1);                                          \
  _Pragma("unroll")                                                       \
  for (int i_ = 0; i_ < 4; ++i_)                                          \
    _Pragma("unroll")                                                     \
    for (int n_ = 0; n_ < 4; ++n_)                                        \
      acc[(MH) * 4 + i_][n_] = __builtin_amdgcn_mfma_f32_16x16x32_bf16(   \
          af[i_], bf[n_], acc[(MH) * 4 + i_][n_], 0, 0, 0);               \
  __builtin_amdgcn_s_setprio(0);

#define PHASE(BUF, KH, MH, DOB, GB, LB, VM)                               \
  do {                                                                    \
    if (DOB) { LOAD_B(BUF, KH) }                                          \
    LOAD_A(BUF, KH, MH)                                                   \
    stage(GB, LB);                                                        \
    if (VM) asm volatile("s_waitcnt vmcnt(6)" ::: "memory");              \
    __builtin_amdgcn_s_barrier();                                         \
    MFMA_Q(MH)                                                            \
    __builtin_amdgcn_sched_barrier(0);                                    \
    __builtin_amdgcn_s_barrier();                                         \
  } while (0)

__global__ __launch_bounds__(512, 2) void gemm_bt_final(
    const __hip_bfloat16* __restrict__ A,  // [M][K] bf16
    const __hip_bfloat16* __restrict__ B,  // [N][K] bf16
    const float* __restrict__ bias,        // [N]
    float* __restrict__ C) {               // [M][N] fp32
  __shared__ __hip_bfloat16 sA[2][2][256][32];  // 64 KiB
  __shared__ __hip_bfloat16 sB[2][2][256][32];  // 64 KiB

  const int tid  = threadIdx.x;
  const int lane = tid & 63;
  const int wave = tid >> 6;
  const int lr = lane & 15;
  const int lk = lane >> 4;
  const int wm = wave >> 2;   // 0..1
  const int wn = wave & 3;    // 0..3
  const int swr = lk ^ ((lr >> 1) & 3);

  // T1: XCD-aware swizzle (nwg=512, %8==0 -> bijective)
  const int bid = blockIdx.x;
  const int cpx = gridDim.x >> 3;
  const int wg  = (bid & 7) * cpx + (bid >> 3);
  const int nbn = GN / BN;    // 16
  const int m0 = (wg / nbn) * BM;
  const int n0 = (wg % nbn) * BN;

  const __hip_bfloat16* Abase = A + (size_t)m0 * GK;
  const __hip_bfloat16* Bbase = B + (size_t)n0 * GK;

  const int swst = (tid >> 3) & 3;
  auto stage = [&](const __hip_bfloat16* gb, __hip_bfloat16* lb) {
    #pragma unroll
    for (int j = 0; j < 2; ++j) {
      const int c = j * 512 + tid;
      const int row = c >> 2, slot = c & 3;
      const int sg = slot ^ swst;
      gload16(gb + (size_t)row * GK + sg * 8,
              (void*)((char*)lb + (j * 512 + wave * 64) * 16));
    }
  };

  f32x4 acc[8][4];
  #pragma unroll
  for (int m = 0; m < 8; ++m)
    #pragma unroll
    for (int n = 0; n < 4; ++n) acc[m][n] = (f32x4)0.0f;

  // Prologue: tile0 fully + tile1 {Bk0, Ak0, Bk1} = 14 VMEM instr;
  // vmcnt(6) -> stages 1-4 complete.
  stage(Abase +  0, &sA[0][0][0][0]);
  stage(Bbase +  0, &sB[0][0][0][0]);
  stage(Abase + 32, &sA[0][1][0][0]);
  stage(Bbase + 32, &sB[0][1][0][0]);
  stage(Bbase + 64, &sB[1][0][0][0]);
  stage(Abase + 64, &sA[1][0][0][0]);
  stage(Bbase + 96, &sB[1][1][0][0]);
  asm volatile("s_waitcnt vmcnt(6)" ::: "memory");
  __builtin_amdgcn_s_barrier();

  short8 af[4], bf[4];

  for (int t = 0; t < NKT; t += 2) {
    const int t2 = (t + 2 < NKT) ? t + 2 : NKT - 1;
    const int t3 = (t + 3 < NKT) ? t + 3 : NKT - 1;

    PHASE(0, 0, 0, true,  Abase + (size_t)(t + 1) * 64 + 32, &sA[1][1][0][0], false);
    PHASE(0, 0, 1, false, Bbase + (size_t)t2 * 64,           &sB[0][0][0][0], false);
    PHASE(0, 1, 0, true,  Abase + (size_t)t2 * 64,           &sA[0][0][0][0], false);
    PHASE(0, 1, 1, false, Bbase + (size_t)t2 * 64 + 32,      &sB[0][1][0][0], true);
    PHASE(1, 0, 0, true,  Abase + (size_t)t2 * 64 + 32,      &sA[0][1][0][0], false);
    PHASE(1, 0, 1, false, Bbase + (size_t)t3 * 64,           &sB[1][0][0][0], false);
    PHASE(1, 1, 0, true,  Abase + (size_t)t3 * 64,           &sA[1][0][0][0], false);
    PHASE(1, 1, 1, false, Bbase + (size_t)t3 * 64 + 32,      &sB[1][1][0][0], true);
  }

  // epilogue: C = acc + bias, nontemporal (don't evict A/B from L2/L3)
  #pragma unroll
  for (int n = 0; n < 4; ++n) {
    const int col = n0 + wn * 64 + n * 16 + lr;
    const float bv = bias[col];
    #pragma unroll
    for (int m = 0; m < 8; ++m) {
      const int row = m0 + wm * 128 + m * 16 + lk * 4;
      #pragma unroll
      for (int j = 0; j < 4; ++j)
        __builtin_nontemporal_store(acc[m][n][j] + bv,
                                    &C[(size_t)(row + j) * GN + col]);
    }
  }
}

// ---------------------------------------------------------------------------
extern "C" void kernel_launch(void* const* d_in, const int* in_sizes, int n_in,
                              void* d_out, int out_size, void* d_ws, size_t ws_size,
                              hipStream_t stream) {
  const float* x    = (const float*)d_in[0];
  const int*   qw   = (const int*)d_in[1];
  const float* wmax = (const float*)d_in[2];
  const float* lut  = (const float*)d_in[3];
  const float* lA   = (const float*)d_in[4];
  const float* lB   = (const float*)d_in[5];
  const float* bias = (const float*)d_in[6];
  float* out = (float*)d_out;

  __hip_bfloat16* Weff = (__hip_bfloat16*)d_ws;                       // 33.5 MB
  __hip_bfloat16* xb   = (__hip_bfloat16*)((char*)d_ws + (size_t)OUT_F * IN_F * 2); // 67 MB

  prep_kernel<<<2560, 256, 0, stream>>>(qw, wmax, lut, lA, lB, x, Weff, xb);
  gemm_bt_final<<<(GM / BM) * (GN / BN), 512, 0, stream>>>(xb, Weff, bias, out);
}

// Round 14
// 302.134 us; speedup vs baseline: 1.1422x; 1.0429x over previous
//
#include <hip/hip_runtime.h>
#include <hip/hip_bf16.h>
#include <stdint.h>

// Problem constants
constexpr int IN_F  = 4096;
constexpr int OUT_F = 4096;
constexpr int M_ROWS = 4 * 2048;   // 8192
constexpr int RANK = 16;

typedef short short8 __attribute__((ext_vector_type(8)));
typedef float f32x4 __attribute__((ext_vector_type(4)));

__device__ __forceinline__ short f2bf(float f) {
  return __builtin_bit_cast(short, __float2bfloat16(f));
}

__device__ __forceinline__ void gload16(const void* g, void* l) {
  __builtin_amdgcn_global_load_lds(
      (const __attribute__((address_space(1))) void*)g,
      (__attribute__((address_space(3))) void*)l, 16, 0, 0);
}

// ---------------------------------------------------------------------------
// Kernel 1 (fused): blocks 0..511 dequantize+LoRA-fold W_eff; blocks 512..2559
// convert x fp32->bf16.
// ---------------------------------------------------------------------------
__global__ __launch_bounds__(256) void prep_kernel(
    const int* __restrict__ q,        // packed bytes, one byte per int32
    const float* __restrict__ wmax,
    const float* __restrict__ lut,
    const float* __restrict__ lA,     // [RANK][IN_F]
    const float* __restrict__ lB,     // [OUT_F][RANK]
    const float* __restrict__ x,
    __hip_bfloat16* __restrict__ W,   // [OUT_F][IN_F]
    __hip_bfloat16* __restrict__ xb) {
  if (blockIdx.x < 512) {
    __shared__ float slut[16];
    if (threadIdx.x < 16) slut[threadIdx.x] = lut[threadIdx.x];
    __syncthreads();

    const int bx = blockIdx.x & 7, by = blockIdx.x >> 3;
    const int o0  = by * 64 + (threadIdx.x >> 5) * 8;
    const int ib0 = bx * 512 + (threadIdx.x & 31) * 16;

    #pragma unroll
    for (int h = 0; h < 2; ++h) {
      const int ib = ib0 + h * 8;
      float w[8][8];
      #pragma unroll
      for (int p = 0; p < 8; ++p) {
        const size_t l = (size_t)(o0 + p) * IN_F + ib;
        const int4 u = *(const int4*)(q + (l >> 1));
        const float sc = wmax[l >> 6];
        w[p][0] = slut[u.x & 15] * sc;
        w[p][1] = slut[(u.x >> 4) & 15] * sc;
        w[p][2] = slut[u.y & 15] * sc;
        w[p][3] = slut[(u.y >> 4) & 15] * sc;
        w[p][4] = slut[u.z & 15] * sc;
        w[p][5] = slut[(u.z >> 4) & 15] * sc;
        w[p][6] = slut[u.w & 15] * sc;
        w[p][7] = slut[(u.w >> 4) & 15] * sc;
      }
      #pragma unroll 2
      for (int r = 0; r < 16; ++r) {
        const float* ar = lA + (size_t)r * IN_F + ib;
        const float4 a0 = *(const float4*)(ar);
        const float4 a1 = *(const float4*)(ar + 4);
        float b[8];
        #pragma unroll
        for (int p = 0; p < 8; ++p) b[p] = lB[(size_t)(o0 + p) * RANK + r];
        #pragma unroll
        for (int p = 0; p < 8; ++p) {
          w[p][0] += b[p] * a0.x; w[p][1] += b[p] * a0.y;
          w[p][2] += b[p] * a0.z; w[p][3] += b[p] * a0.w;
          w[p][4] += b[p] * a1.x; w[p][5] += b[p] * a1.y;
          w[p][6] += b[p] * a1.z; w[p][7] += b[p] * a1.w;
        }
      }
      #pragma unroll
      for (int p = 0; p < 8; ++p) {
        short8 s;
        #pragma unroll
        for (int qq = 0; qq < 8; ++qq) s[qq] = f2bf(w[p][qq]);
        *(short8*)&W[(size_t)(o0 + p) * IN_F + ib] = s;
      }
    }
  } else {
    constexpr int NG = (M_ROWS * IN_F) / 8;
    const int stride = 2048 * 256;
    for (int i = (blockIdx.x - 512) * 256 + threadIdx.x; i < NG; i += stride) {
      const float4 a = ((const float4*)x)[2 * i];
      const float4 b = ((const float4*)x)[2 * i + 1];
      short8 s;
      s[0] = f2bf(a.x); s[1] = f2bf(a.y); s[2] = f2bf(a.z); s[3] = f2bf(a.w);
      s[4] = f2bf(b.x); s[5] = f2bf(b.y); s[6] = f2bf(b.z); s[7] = f2bf(b.w);
      ((short8*)xb)[i] = s;
    }
  }
}

// ---------------------------------------------------------------------------
// Kernel 2: 256x256-tile 8-phase GEMM — OVERLAP variant (single barrier +
// read-ahead + counted lgkm).  Phase p: [stage; vm@p4,p8; BAR; ds_reads for
// phase p+1 -> alt frag buffers; lgkmcnt(N_issued) (drains p-1's frags, p's
// stay in flight UNDER the MFMA); MFMA(p); NO end barrier].
// A-frags alternate per phase (af[p&1]); B-frags per pair (bf[pair&1]).
// Audited: read-publish (vmcnt+BAR >=1 phase ahead for all 8 phases), WAR
// (>=1 barrier + ~300cy gload latency between last read-issue and re-stage),
// vmcnt ledger identical to R5.  Rule-18 sched_barrier(0) after asm lgkmcnt.
// ---------------------------------------------------------------------------
constexpr int BM = 256, BN = 256, BK = 64;
constexpr int GM = M_ROWS, GN = OUT_F, GK = IN_F;
constexpr int NKT = GK / BK;  // 64

#define LOAD_Bn(RB_, RKH, DST)                                            \
  _Pragma("unroll")                                                       \
  for (int n_ = 0; n_ < 4; ++n_)                                          \
    bfr[DST][n_] = *(const short8*)&sB[RB_][RKH][wn * 64 + n_ * 16 + lr][swr * 8];

#define LOAD_An(RB_, RKH, RMH, DST)                                       \
  _Pragma("unroll")                                                       \
  for (int i_ = 0; i_ < 4; ++i_)                                          \
    afr[DST][i_] = *(const short8*)&sA[RB_][RKH][wm * 128 + (RMH) * 64 + i_ * 16 + lr][swr * 8];

#define MFMA_Q(CMH, AC, BC)                                               \
  __builtin_amdgcn_s_setprio(1);                                          \
  _Pragma("unroll")                                                       \
  for (int i_ = 0; i_ < 4; ++i_)                                          \
    _Pragma("unroll")                                                     \
    for (int n_ = 0; n_ < 4; ++n_)                                        \
      acc[(CMH) * 4 + i_][n_] = __builtin_amdgcn_mfma_f32_16x16x32_bf16(  \
          afr[AC][i_], bfr[BC][n_], acc[(CMH) * 4 + i_][n_], 0, 0, 0);    \
  __builtin_amdgcn_s_setprio(0);

// AC/BC: frag buffers this phase's MFMA consumes. Reads for next phase go to
// AC^1 (and BC^1 when NDOB). NBUF/NKH/NMH: LDS region of next phase's frags.
// NLG = reads issued this phase (4 or 8) = lgkmcnt wait value.
#define PHASE(AC, BC, NDOB, NBUF, NKH, NMH, CMH, GB, LB, VM, NLG)         \
  do {                                                                    \
    stage(GB, LB);                                                        \
    if (VM) asm volatile("s_waitcnt vmcnt(6)" ::: "memory");              \
    __builtin_amdgcn_s_barrier();                                         \
    if (NDOB) { LOAD_Bn(NBUF, NKH, (BC) ^ 1) }                            \
    LOAD_An(NBUF, NKH, NMH, (AC) ^ 1)                                     \
    asm volatile("s_waitcnt lgkmcnt(" #NLG ")" ::: "memory");             \
    __builtin_amdgcn_sched_barrier(0);                                    \
    MFMA_Q(CMH, AC, BC)                                                   \
  } while (0)

__global__ __launch_bounds__(512, 2) void gemm_bt_ovl(
    const __hip_bfloat16* __restrict__ A,  // [M][K] bf16
    const __hip_bfloat16* __restrict__ B,  // [N][K] bf16
    const float* __restrict__ bias,        // [N]
    float* __restrict__ C) {               // [M][N] fp32
  __shared__ __hip_bfloat16 sA[2][2][256][32];  // 64 KiB
  __shared__ __hip_bfloat16 sB[2][2][256][32];  // 64 KiB

  const int tid  = threadIdx.x;
  const int lane = tid & 63;
  const int wave = tid >> 6;
  const int lr = lane & 15;
  const int lk = lane >> 4;
  const int wm = wave >> 2;   // 0..1
  const int wn = wave & 3;    // 0..3
  const int swr = lk ^ ((lr >> 1) & 3);

  // T1: XCD-aware swizzle (nwg=512, %8==0 -> bijective)
  const int bid = blockIdx.x;
  const int cpx = gridDim.x >> 3;
  const int wg  = (bid & 7) * cpx + (bid >> 3);
  const int nbn = GN / BN;    // 16
  const int m0 = (wg / nbn) * BM;
  const int n0 = (wg % nbn) * BN;

  const __hip_bfloat16* Abase = A + (size_t)m0 * GK;
  const __hip_bfloat16* Bbase = B + (size_t)n0 * GK;

  const int swst = (tid >> 3) & 3;
  auto stage = [&](const __hip_bfloat16* gb, __hip_bfloat16* lb) {
    #pragma unroll
    for (int j = 0; j < 2; ++j) {
      const int c = j * 512 + tid;
      const int row = c >> 2, slot = c & 3;
      const int sg = slot ^ swst;
      gload16(gb + (size_t)row * GK + sg * 8,
              (void*)((char*)lb + (j * 512 + wave * 64) * 16));
    }
  };

  f32x4 acc[8][4];
  #pragma unroll
  for (int m = 0; m < 8; ++m)
    #pragma unroll
    for (int n = 0; n < 4; ++n) acc[m][n] = (f32x4)0.0f;

  // Prologue: tile0 fully + tile1 {Bk0, Ak0, Bk1} = 14 VMEM instr;
  // vmcnt(6) -> dbuf0 (both halves) complete before the barrier.
  stage(Abase +  0, &sA[0][0][0][0]);
  stage(Bbase +  0, &sB[0][0][0][0]);
  stage(Abase + 32, &sA[0][1][0][0]);
  stage(Bbase + 32, &sB[0][1][0][0]);
  stage(Bbase + 64, &sB[1][0][0][0]);
  stage(Abase + 64, &sA[1][0][0][0]);
  stage(Bbase + 96, &sB[1][1][0][0]);
  asm volatile("s_waitcnt vmcnt(6)" ::: "memory");
  __builtin_amdgcn_s_barrier();

  short8 afr[2][4], bfr[2][4];
  // pre-load phase-1 frags: A(0,0,MH0) -> af[1], B(0,0) -> bf[0]
  LOAD_Bn(0, 0, 0)
  LOAD_An(0, 0, 0, 1)

  for (int t = 0; t < NKT; t += 2) {
    const int t2 = (t + 2 < NKT) ? t + 2 : NKT - 1;
    const int t3 = (t + 3 < NKT) ? t + 3 : NKT - 1;

    //    AC BC ND NB NK NM CM  stage-src                            stage-dst        VM NLG
    PHASE(1, 0, 0, 0, 0, 1, 0,  Abase + (size_t)(t + 1) * 64 + 32, &sA[1][1][0][0], 0, 4);
    PHASE(0, 0, 1, 0, 1, 0, 1,  Bbase + (size_t)t2 * 64,           &sB[0][0][0][0], 0, 8);
    PHASE(1, 1, 0, 0, 1, 1, 0,  Abase + (size_t)t2 * 64,           &sA[0][0][0][0], 0, 4);
    PHASE(0, 1, 1, 1, 0, 0, 1,  Bbase + (size_t)t2 * 64 + 32,      &sB[0][1][0][0], 1, 8);
    PHASE(1, 0, 0, 1, 0, 1, 0,  Abase + (size_t)t2 * 64 + 32,      &sA[0][1][0][0], 0, 4);
    PHASE(0, 0, 1, 1, 1, 0, 1,  Bbase + (size_t)t3 * 64,           &sB[1][0][0][0], 0, 8);
    PHASE(1, 1, 0, 1, 1, 1, 0,  Abase + (size_t)t3 * 64,           &sA[1][0][0][0], 0, 4);
    PHASE(0, 1, 1, 0, 0, 0, 1,  Bbase + (size_t)t3 * 64 + 32,      &sB[1][1][0][0], 1, 8);
  }

  // epilogue: C = acc + bias, nontemporal
  #pragma unroll
  for (int n = 0; n < 4; ++n) {
    const int col = n0 + wn * 64 + n * 16 + lr;
    const float bv = bias[col];
    #pragma unroll
    for (int m = 0; m < 8; ++m) {
      const int row = m0 + wm * 128 + m * 16 + lk * 4;
      #pragma unroll
      for (int j = 0; j < 4; ++j)
        __builtin_nontemporal_store(acc[m][n][j] + bv,
                                    &C[(size_t)(row + j) * GN + col]);
    }
  }
}

// ---------------------------------------------------------------------------
extern "C" void kernel_launch(void* const* d_in, const int* in_sizes, int n_in,
                              void* d_out, int out_size, void* d_ws, size_t ws_size,
                              hipStream_t stream) {
  const float* x    = (const float*)d_in[0];
  const int*   qw   = (const int*)d_in[1];
  const float* wmax = (const float*)d_in[2];
  const float* lut  = (const float*)d_in[3];
  const float* lA   = (const float*)d_in[4];
  const float* lB   = (const float*)d_in[5];
  const float* bias = (const float*)d_in[6];
  float* out = (float*)d_out;

  __hip_bfloat16* Weff = (__hip_bfloat16*)d_ws;                       // 33.5 MB
  __hip_bfloat16* xb   = (__hip_bfloat16*)((char*)d_ws + (size_t)OUT_F * IN_F * 2); // 67 MB

  prep_kernel<<<2560, 256, 0, stream>>>(qw, wmax, lut, lA, lB, x, Weff, xb);
  gemm_bt_ovl<<<(GM / BM) * (GN / BN), 512, 0, stream>>>(xb, Weff, bias, out);
}